// Round 11
// baseline (223.323 us; speedup 1.0000x reference)
//
#include <hip/hip_runtime.h>

// PermuteWeightSharing: out[row, s*16+k] = x[row, ppos[s]*16+k] - x[row, pneg[s]*16+k]
// row = (b,o,i) flattened, 256 floats per row = 16 slots x 16 floats = 64 float4.
//
// v12 = v9 verbatim (best of 11 variants, bench 219.4 us).
// Structure: 32768 blocks x 256 threads, 1 float4/thread, zero preamble --
// the x-load issues at cycle 0 (sequential, permutation-independent); the
// permutation is decoded per-wave fully in-register via 3 ballots (no LDS,
// no __syncthreads) overlapping the x-load latency; applied post-load with
// 8 ds_bpermute; plain stores.
// Session ledger (bench us): v0 223.6 | grid-stride loop 239 | MLP4 231 |
// seq+bpermute 230 | +NT 233 | MLP2 228 | zero-preamble@8192blk 231 |
// v9 219.4 | block=1024 224 | scattered-order 222.4.
// Levers tested-null: NT stores, access pattern, MLP, in-flight bytes,
// block size up, decode ordering. The win: zero-preamble x max-TLP.

#define NSLOTS 16

typedef float fvec4 __attribute__((ext_vector_type(4)));

__device__ inline fvec4 lane_gather(fvec4 a, int byte_addr)
{
    fvec4 r;
    r.x = __int_as_float(__builtin_amdgcn_ds_bpermute(byte_addr, __float_as_int(a.x)));
    r.y = __int_as_float(__builtin_amdgcn_ds_bpermute(byte_addr, __float_as_int(a.y)));
    r.z = __int_as_float(__builtin_amdgcn_ds_bpermute(byte_addr, __float_as_int(a.z)));
    r.w = __int_as_float(__builtin_amdgcn_ds_bpermute(byte_addr, __float_as_int(a.w)));
    return r;
}

// Wave-cooperative one-hot decode: lane l holds float4 #l of a 16x16
// row-major perm matrix (row = l>>2, cols (l&3)*4..+3). Returns the hot
// column of row `slot` == perm[slot].
__device__ inline int decode_col(const fvec4 pr, int slot)
{
    int  h    = 0;
    bool pres = false;
    if (pr.x > 0.5f) { h = 0; pres = true; }
    if (pr.y > 0.5f) { h = 1; pres = true; }
    if (pr.z > 0.5f) { h = 2; pres = true; }
    if (pr.w > 0.5f) { h = 3; pres = true; }
    const unsigned long long bp = __ballot(pres);     // which lane(s) hold row's hot chunk
    const unsigned long long b0 = __ballot(h & 1);    // low bit of within-chunk idx
    const unsigned long long b1 = __ballot(h >> 1);   // high bit
    const int nib = (int)((bp >> (slot * 4)) & 0xFull);      // my row's 4 lanes
    const int cl  = slot * 4 + __builtin_ctz(nib);           // hot chunk's lane
    const int hh  = (int)((b0 >> cl) & 1ull) | ((int)((b1 >> cl) & 1ull) << 1);
    return ((cl & 3) << 2) | hh;                             // col in [0,16)
}

__global__ __launch_bounds__(256, 8) void permute_ws_kernel(
    const fvec4* __restrict__ x,
    const float* __restrict__ Ppos,
    const float* __restrict__ Pneg,
    fvec4* __restrict__ out,
    int total_v4)
{
    const int t    = threadIdx.x;
    const int lane = t & 63;
    const int i    = blockIdx.x * 256 + t;   // 1 float4 per thread

    // total_v4 is a multiple of 64 (whole rows), so this guard is
    // wave-uniform: ballots/bpermutes below always see all 64 lanes.
    if (i >= total_v4) return;

    // ---- x load FIRST: sequential, permutation-independent, cycle-0 issue ----
    const fvec4 a = x[i];

    // ---- decode overlaps the x-load latency (no LDS, no barrier) ----
    const fvec4 prp = ((const fvec4*)Ppos)[lane];   // 64 lanes x 16B = whole matrix
    const fvec4 prn = ((const fvec4*)Pneg)[lane];
    const int slot = lane >> 2;
    const int k4   = lane & 3;
    const int colp = decode_col(prp, slot);
    const int coln = decode_col(prn, slot);
    // source lane holding input float4 (4*col + k4); bpermute addr = lane*4
    const int bpa = (((colp << 2) | k4) << 2);
    const int bna = (((coln << 2) | k4) << 2);

    out[i] = lane_gather(a, bpa) - lane_gather(a, bna);
}

extern "C" void kernel_launch(void* const* d_in, const int* in_sizes, int n_in,
                              void* d_out, int out_size, void* d_ws, size_t ws_size,
                              hipStream_t stream)
{
    const fvec4* x    = (const fvec4*)d_in[0];
    const float* Ppos = (const float*)d_in[1];
    const float* Pneg = (const float*)d_in[2];
    fvec4*       out  = (fvec4*)d_out;

    const int total_v4 = out_size / 4;   // 33,554,432 / 4 = 8,388,608

    const int block = 256;
    const int grid  = (total_v4 + block - 1) / block;   // 32768, exact fit

    permute_ws_kernel<<<grid, block, 0, stream>>>(x, Ppos, Pneg, out, total_v4);
}